// Round 12
// baseline (143.864 us; speedup 1.0000x reference)
//
#include <hip/hip_runtime.h>
#include <hip/hip_bf16.h>

#define BB 16
#define EE 128
#define MM 64
#define DQ 768
#define DK 256

typedef __attribute__((ext_vector_type(8))) short short8v;    // 8 bf16 = 4 VGPR
typedef __attribute__((ext_vector_type(4))) float f32x4;
typedef __attribute__((ext_vector_type(16))) float f32x16;

#define MFMA16(a, b, c) __builtin_amdgcn_mfma_f32_16x16x32_bf16(a, b, c, 0, 0, 0)
#define MFMA32(a, b, c) __builtin_amdgcn_mfma_f32_32x32x16_bf16(a, b, c, 0, 0, 0)

// raw barrier: LDS visibility only; leaves global loads/stores in flight
#define LDS_BARRIER() asm volatile("s_waitcnt lgkmcnt(0)\n\ts_barrier" ::: "memory")

__device__ __forceinline__ ushort f2bf(float f) {
  __hip_bfloat16 h = __float2bfloat16(f);
  return *reinterpret_cast<ushort*>(&h);
}
__device__ __forceinline__ uint pack2(float lo, float hi) {
  return (uint)f2bf(lo) | ((uint)f2bf(hi) << 16);
}

// ---------------------------------------------------------------------------
// K1: WfT[e][d] = sum_k Wq[d][k] * Wk[e][k]  (= (Wq @ Wk^T)^T, bf16) via MFMA.
// ---------------------------------------------------------------------------
__global__ __launch_bounds__(64) void k_wfuse(const float* __restrict__ Wq,
                                              const float* __restrict__ Wk,
                                              ushort* __restrict__ wfT) {
  const int lane = threadIdx.x & 63;
  const int lo = lane & 15, hi = lane >> 4;
  const int e0 = blockIdx.x * 16;
  const int d0 = blockIdx.y * 64;
  f32x4 acc[4] = {f32x4{0.f, 0.f, 0.f, 0.f}, f32x4{0.f, 0.f, 0.f, 0.f},
                  f32x4{0.f, 0.f, 0.f, 0.f}, f32x4{0.f, 0.f, 0.f, 0.f}};
#pragma unroll
  for (int ks = 0; ks < 8; ++ks) {
    const int k = ks * 32 + 8 * hi;
    const float4 a0 = *(const float4*)&Wk[(size_t)(e0 + lo) * DK + k];
    const float4 a1 = *(const float4*)&Wk[(size_t)(e0 + lo) * DK + k + 4];
    union { short8v v; uint u[4]; } av;
    av.u[0] = pack2(a0.x, a0.y); av.u[1] = pack2(a0.z, a0.w);
    av.u[2] = pack2(a1.x, a1.y); av.u[3] = pack2(a1.z, a1.w);
#pragma unroll
    for (int dt = 0; dt < 4; ++dt) {
      const float4 b0 = *(const float4*)&Wq[(size_t)(d0 + dt * 16 + lo) * DK + k];
      const float4 b1 = *(const float4*)&Wq[(size_t)(d0 + dt * 16 + lo) * DK + k + 4];
      union { short8v v; uint u[4]; } bv;
      bv.u[0] = pack2(b0.x, b0.y); bv.u[1] = pack2(b0.z, b0.w);
      bv.u[2] = pack2(b1.x, b1.y); bv.u[3] = pack2(b1.z, b1.w);
      acc[dt] = MFMA16(av.v, bv.v, acc[dt]);
    }
  }
#pragma unroll
  for (int dt = 0; dt < 4; ++dt)
#pragma unroll
    for (int r = 0; r < 4; ++r)
      wfT[(size_t)(e0 + 4 * hi + r) * DQ + d0 + dt * 16 + lo] = f2bf(acc[dt][r]);
}

// ---------------------------------------------------------------------------
// K2: qt2[r][e] = (sum_d relu(querys[r][d]) * WfT[e][d]) * scale + Wm_w[e].
// Scale + mention-bias weight folded into the query side (f32 fold, bf16 out).
// ---------------------------------------------------------------------------
__global__ __launch_bounds__(128) void k_qt(const float* __restrict__ querys,
                                            const ushort* __restrict__ wfT,
                                            const float* __restrict__ wm_w,
                                            ushort* __restrict__ qt) {
  const int tid = threadIdx.x;
  const int w = tid >> 6;
  const int lane = tid & 63;
  const int lo = lane & 15, hi = lane >> 4;
  const int r0 = blockIdx.x * 32 + w * 16;
  const int e0 = blockIdx.y * 64;
  const float* qrow = querys + (size_t)(r0 + lo) * DQ;
  f32x4 acc[4] = {f32x4{0.f, 0.f, 0.f, 0.f}, f32x4{0.f, 0.f, 0.f, 0.f},
                  f32x4{0.f, 0.f, 0.f, 0.f}, f32x4{0.f, 0.f, 0.f, 0.f}};
#pragma unroll
  for (int kc = 0; kc < DQ; kc += 32) {
    const int k = kc + 8 * hi;
    const float4 a0 = *(const float4*)&qrow[k];
    const float4 a1 = *(const float4*)&qrow[k + 4];
    union { short8v v; uint u[4]; } af;
    af.u[0] = pack2(fmaxf(a0.x, 0.f), fmaxf(a0.y, 0.f));
    af.u[1] = pack2(fmaxf(a0.z, 0.f), fmaxf(a0.w, 0.f));
    af.u[2] = pack2(fmaxf(a1.x, 0.f), fmaxf(a1.y, 0.f));
    af.u[3] = pack2(fmaxf(a1.z, 0.f), fmaxf(a1.w, 0.f));
#pragma unroll
    for (int et = 0; et < 4; ++et) {
      const short8v bf = *(const short8v*)&wfT[(size_t)(e0 + et * 16 + lo) * DQ + k];
      acc[et] = MFMA16(af.v, bf, acc[et]);
    }
  }
  const float sc = 0.036084391824351615f;  // 1/sqrt(768)
#pragma unroll
  for (int et = 0; et < 4; ++et) {
    const float wmv = wm_w[e0 + et * 16 + lo];
#pragma unroll
    for (int r = 0; r < 4; ++r)
      qt[(size_t)(r0 + hi * 4 + r) * DK + e0 + et * 16 + lo] =
          f2bf(fmaf(acc[et][r], sc, wmv));
  }
}

// ---------------------------------------------------------------------------
// K3: fused MFMA attention, LDS-diet edition. 512 thr = 8 waves, one (b,a)
// per block, grid 2048. LDS = raw keys 32K + P 16K = 48 KiB -> 3 blocks/CU
// (24 waves, vs 2 blocks/16 waves at the old 80 KiB). Keys stored ONCE as
// raw bf16 [m][d], swizzle sw(m) = ((m&7)^(((m>>3)&1)<<2))<<4 on bytes 4-6:
//   - QK reads row fragments (conflict-free) and applies relu IN-REGISTER:
//     bf16 relu == max_i16(bits, 0)  (sign bit -> clamps to +0).
//   - PV gathers B-fragments column-wise (8 x ds_read_u16); the bit-6 row
//     swizzle puts m and m+8 in opposite 64B halves -> conflict-free.
// Flow: stage | BAR1 | QK(swapped 16x16) -> softmax(+mask) -> P->P_lds |
//       BAR2 | PV 32x32 C[q][d] (full-128B-line stores).
// __launch_bounds__(512,6): 6 waves/EU -> 3 blocks/CU; VGPR cap ~85
// (peak live audited ~70; masks loaded after QK to cut liveness).
// ---------------------------------------------------------------------------
__global__ __launch_bounds__(512, 6) void k_attn(
    const float* __restrict__ keys, const ushort* __restrict__ qt,
    const int* __restrict__ masks, float* __restrict__ out) {
  __shared__ ushort key_lds[MM * DK];    // 32 KiB raw bf16, swizzled
  __shared__ ushort P_lds[EE * MM];      // 16 KiB, swz ((q&7)^((q>>3)&7))<<4

  const int tid = threadIdx.x;
  const int w = tid >> 6;
  const int lane = tid & 63;
  const int lo = lane & 15, hi = lane >> 4;
  const int ba = blockIdx.x;             // b*EE + a
  const int b = ba >> 7;

  // ================= stage: keys -> key_lds (raw bf16, swizzled) ===========
  // 16-lane group hi of wave w owns row pair (m0, m0+1); lane lo covers
  // f32x4 chunks c = lo + 16*it (8 bf16 bytes each).
  {
    const int m0 = w * 8 + hi * 2;
    const int sw0 = ((m0 & 7) ^ (((m0 >> 3) & 1) << 2)) << 4;
    const int sw1 = (((m0 + 1) & 7) ^ ((((m0 + 1) >> 3) & 1) << 2)) << 4;
    const float4* kb4 = (const float4*)(keys + (size_t)ba * (MM * DK));
#pragma unroll
    for (int it = 0; it < 4; ++it) {
      const int c = lo + 16 * it;
      const float4 va = kb4[(size_t)m0 * 64 + c];
      const float4 vb = kb4[(size_t)(m0 + 1) * 64 + c];
      uint2 ra, rb;
      ra.x = pack2(va.x, va.y); ra.y = pack2(va.z, va.w);
      rb.x = pack2(vb.x, vb.y); rb.y = pack2(vb.z, vb.w);
      *(uint2*)((char*)key_lds + (size_t)m0 * 512 + ((8 * c) ^ sw0)) = ra;
      *(uint2*)((char*)key_lds + (size_t)(m0 + 1) * 512 + ((8 * c) ^ sw1)) = rb;
    }
  }

  // qt2 B-fragments for QK (cols q = w*16+lo); issued while barrier drains
  const ushort* qrowp = qt + ((size_t)b * EE + w * 16 + lo) * DK + 8 * hi;
  short8v aq[8];
#pragma unroll
  for (int ks = 0; ks < 8; ++ks) aq[ks] = *(const short8v*)(qrowp + 32 * ks);

  LDS_BARRIER();   // BAR1: staging visible

  // ====== QK^T swapped 16x16: full logits S^T[m][q], lane q = w*16+lo ======
  // B-operand = relu(keys) applied in-register via packed i16 max.
  const short8v zero8 = {0, 0, 0, 0, 0, 0, 0, 0};
  const int swm = ((lo & 7) ^ (((lo >> 3) & 1) << 2)) << 4;  // sw(m=mt*16+lo)
  f32x4 sacc[4] = {f32x4{0.f, 0.f, 0.f, 0.f}, f32x4{0.f, 0.f, 0.f, 0.f},
                   f32x4{0.f, 0.f, 0.f, 0.f}, f32x4{0.f, 0.f, 0.f, 0.f}};
  __builtin_amdgcn_s_setprio(1);
#pragma unroll
  for (int ks = 0; ks < 8; ++ks) {
#pragma unroll
    for (int mt = 0; mt < 4; ++mt) {
      const int m = mt * 16 + lo;
      short8v bf = *(const short8v*)((char*)key_lds + (size_t)m * 512 +
                                     ((((ks * 4 + hi) << 4)) ^ swm));
      bf = __builtin_elementwise_max(bf, zero8);   // bf16 relu (i16 max vs 0)
      sacc[mt] = MFMA16(bf, aq[ks], sacc[mt]);     // A = relu_k, B = qt2
    }
  }
  __builtin_amdgcn_s_setprio(0);

  // mask bits for this lane's softmax rows: m = mt*16 + hi*4 .. +3
  const int4* mrow = (const int4*)(masks + (size_t)ba * MM);
  int4 mk4[4];
#pragma unroll
  for (int mt = 0; mt < 4; ++mt) mk4[mt] = mrow[mt * 4 + hi];

  // ============ softmax: mask select, in-lane 16 m + shfl_xor 16,32 ========
  float l[4][4];
  float mx = -3.4e38f;
#pragma unroll
  for (int mt = 0; mt < 4; ++mt) {
    const int mkb[4] = {mk4[mt].x, mk4[mt].y, mk4[mt].z, mk4[mt].w};
#pragma unroll
    for (int r = 0; r < 4; ++r) {
      l[mt][r] = (mkb[r] != 0) ? sacc[mt][r] : -1e30f;
      mx = fmaxf(mx, l[mt][r]);
    }
  }
  mx = fmaxf(mx, __shfl_xor(mx, 16));
  mx = fmaxf(mx, __shfl_xor(mx, 32));
  float s = 0.f;
#pragma unroll
  for (int mt = 0; mt < 4; ++mt)
#pragma unroll
    for (int r = 0; r < 4; ++r) {
      l[mt][r] = __expf(l[mt][r] - mx);
      s += l[mt][r];
    }
  s += __shfl_xor(s, 16);
  s += __shfl_xor(s, 32);
  const float rinv = 1.f / s;

  // ================= P -> P_lds (bf16, swizzled rows of 128B) ==============
  {
    const int q = w * 16 + lo;
    const int swq = ((q & 7) ^ ((q >> 3) & 7)) << 4;
#pragma unroll
    for (int mt = 0; mt < 4; ++mt) {
      uint2 pv;
      pv.x = pack2(l[mt][0] * rinv, l[mt][1] * rinv);
      pv.y = pack2(l[mt][2] * rinv, l[mt][3] * rinv);  // m = mt*16+hi*4 .. +3
      *(uint2*)((char*)P_lds + (size_t)q * 128 +
                ((32 * mt + 8 * hi) ^ swq)) = pv;
    }
  }
  LDS_BARRIER();   // BAR2: P complete

  // ================= PV: NON-swapped 32x32x16, C[q][d] =====================
  // wave w: q-block qb=(w&3)*32, d-range db=(w>>2)*128 (4 tiles of 32 d).
  // A (P) from P_lds rows; B (raw keys, col-major) GATHERED from key_lds:
  //   bk.u16[j] = keys_bf16[ms*16 + 8*lh + j][d],
  //   addr(j) = (A0 ^ (j<<4)) + j*512,  A0 = mbase*512 + (d&7)*2 + (c0<<4),
  //   c0 = (d>>3) ^ (lh<<2)   (conflict-free: m/m+8 in opposite 64B halves).
  // C: col d = lane&31 -> each per-reg store = 32 consecutive d = 128B line.
  {
    const int l31 = lane & 31, lh = lane >> 5;
    const int qb = (w & 3) * 32;
    const int db = (w >> 2) * 128;
    const int qa = qb + l31;
    const int swqa = ((qa & 7) ^ ((qa >> 3) & 7)) << 4;
    short8v pa[4];
#pragma unroll
    for (int ms = 0; ms < 4; ++ms)
      pa[ms] = *(const short8v*)((char*)P_lds + (size_t)qa * 128 +
                                 ((32 * ms + 16 * lh) ^ swqa));
    float* ob = out + (size_t)ba * EE * DK;
    __builtin_amdgcn_s_setprio(1);
#pragma unroll
    for (int t = 0; t < 4; ++t) {
      const int d = db + t * 32 + l31;
      const uint c0 = (uint)((d >> 3) ^ (lh << 2));
      f32x16 o = 0.f;
#pragma unroll
      for (int ms = 0; ms < 4; ++ms) {
        const uint A0 = (uint)(ms * 16 + 8 * lh) * 512 + ((uint)(d & 7) << 1) +
                        (c0 << 4);
        union { short8v v; uint u[4]; } bk;
#pragma unroll
        for (int jj = 0; jj < 4; ++jj) {
          const int j0 = 2 * jj, j1 = 2 * jj + 1;
          const uint s0 = *(const ushort*)((const char*)key_lds +
                                           ((A0 ^ (j0 << 4)) + (j0 << 9)));
          const uint s1 = *(const ushort*)((const char*)key_lds +
                                           ((A0 ^ (j1 << 4)) + (j1 << 9)));
          bk.u[jj] = s0 | (s1 << 16);
        }
        o = MFMA32(pa[ms], bk.v, o);
      }
#pragma unroll
      for (int r = 0; r < 16; ++r) {
        const int qrow = qb + (r & 3) + 8 * (r >> 2) + 4 * lh;
        ob[(size_t)qrow * DK + d] = o[r];
      }
    }
    __builtin_amdgcn_s_setprio(0);
  }
}

// ---------------------------------------------------------------------------
extern "C" void kernel_launch(void* const* d_in, const int* in_sizes, int n_in,
                              void* d_out, int out_size, void* d_ws, size_t ws_size,
                              hipStream_t stream) {
  const float* querys = (const float*)d_in[0];  // [16,128,768]
  const float* keys   = (const float*)d_in[1];  // [16,128,64,256]
  const float* Wq     = (const float*)d_in[2];  // [768,256]
  const float* Wk     = (const float*)d_in[3];  // [256,256]
  const float* Wm_w   = (const float*)d_in[4];  // [256]
  // d_in[5] = Wm_b: row-constant logit shift -> cancels in softmax; unused.
  const int*   masks  = (const int*)d_in[6];    // [16,128,64]
  float* out = (float*)d_out;                   // [16,128,128,256]

  ushort* wfT   = (ushort*)d_ws;                          // 256*768 bf16
  ushort* qt_bf = (ushort*)((char*)d_ws + DK * DQ * 2);   // 2048*256 bf16

  k_wfuse<<<dim3(DK / 16, DQ / 64), 64, 0, stream>>>(Wq, Wk, wfT);
  k_qt<<<dim3((BB * EE) / 32, DK / 64), 128, 0, stream>>>(querys, wfT, Wm_w, qt_bf);
  k_attn<<<BB * EE, 512, 0, stream>>>(keys, qt_bf, masks, out);
}